// Round 3
// baseline (375954.810 us; speedup 1.0000x reference)
//
#include <hip/hip_runtime.h>
#include <math.h>

// ---- problem constants ----
constexpr int SEQ_T  = 2048;
constexpr int BATCH  = 128;
constexpr int KDIM   = 128;
constexpr int VDIM   = 128;
constexpr int EDIM   = 400;
constexpr int HDIM   = 300;
constexpr int GDIM   = 1200;    // 4*H
constexpr int NVOCAB = 33;
constexpr int MAXLEN = 500;
constexpr int SOS_TOK = 5;
constexpr int NBLK = 256;       // one block per CU; co-residency has 2x headroom
constexpr int NTHR = 512;
constexpr long long NLOGITS = (long long)MAXLEN * BATCH * NVOCAB; // 2,112,000

// ---- ws float-element offsets ----
constexpr size_t OFF_H      = 0;        // 128*300
constexpr size_t OFF_C      = 38400;    // 128*300
constexpr size_t OFF_GATES  = 76800;    // 128*1200
constexpr size_t OFF_QUERY  = 230400;   // 128*128
constexpr size_t OFF_ENERGY = 246784;   // 128*2048
constexpr size_t OFF_CTX    = 508928;   // 128*128
constexpr size_t OFF_WPHIT  = 525312;   // 300*128
constexpr size_t OFF_CHARS  = 563712;   // 128 int
constexpr size_t OFF_BAR    = 563840;   // 1 u32 (zeroed via hipMemsetAsync)

// ---------------------------------------------------------------------------
// device-scope grid barrier: monotone counter, unique target per barrier.
// All 256 blocks execute the same barrier sequence.
__device__ __forceinline__ void gbar(unsigned* cnt, unsigned target) {
  __threadfence();                 // release this thread's prior global writes
  __syncthreads();                 // whole block done with phase
  if (threadIdx.x == 0) {
    __hip_atomic_fetch_add(cnt, 1u, __ATOMIC_ACQ_REL, __HIP_MEMORY_SCOPE_AGENT);
    while (__hip_atomic_load(cnt, __ATOMIC_ACQUIRE, __HIP_MEMORY_SCOPE_AGENT) < target) {
      __builtin_amdgcn_s_sleep(8); // ~512 cy between polls: low fabric traffic
    }
  }
  __syncthreads();
  __threadfence();                 // acquire: invalidate stale cached lines
}

// ---------------------------------------------------------------------------
// energy[b][t] = query[b,:] . keys[t,b,:]  — streams keys (134 MB)
// virtual grid 1024 = 128 b x 8 t-octants; each block does 4 virtual tiles.
__device__ __forceinline__ void phase_energy(
    const float* __restrict__ keys, const float* __restrict__ query,
    float* __restrict__ energy, int blk, int tid) {
  const int wave = tid >> 6, lane = tid & 63;
  const int half = lane >> 5, l32 = lane & 31;
  for (int it = 0; it < 4; ++it) {
    const int v = blk + it * NBLK;       // 0..1023
    const int b = v & 127, t8 = v >> 7;  // t8 in 0..7
    const float4 q4 = *(const float4*)(query + b * KDIM + l32 * 4);
    const int t0 = t8 * 256 + wave * 32;
    for (int i = 0; i < 16; ++i) {
      const int t = t0 + 2 * i + half;
      const float4 kv = *(const float4*)(keys + ((size_t)t * BATCH + b) * KDIM + l32 * 4);
      float p = q4.x * kv.x + q4.y * kv.y + q4.z * kv.z + q4.w * kv.w;
      p += __shfl_xor(p, 1);
      p += __shfl_xor(p, 2);
      p += __shfl_xor(p, 4);
      p += __shfl_xor(p, 8);
      p += __shfl_xor(p, 16);
      if (l32 == 0) energy[b * SEQ_T + t] = p;
    }
  }
}

// fused softmax + context — streams values (134 MB)
// block = (vhalf, b); softmax recomputed per block (deterministic, identical
// across the two vhalf blocks of a b).
__device__ __forceinline__ void phase_context(
    const float* __restrict__ values, const float* __restrict__ energy,
    float* __restrict__ ctx, float* smem, int blk, int tid) {
  const int vhalf = blk >> 7, b = blk & 127;
  float* att  = smem;            // 2048
  float* red  = smem + 2048;     // 16
  float* redv = smem + 2080;     // 32 x 17 float4 = 2176 floats
  float e4[4];
  float m = -INFINITY;
#pragma unroll
  for (int i = 0; i < 4; ++i) {
    e4[i] = energy[b * SEQ_T + i * 512 + tid];
    m = fmaxf(m, e4[i]);
  }
  for (int off = 32; off; off >>= 1) m = fmaxf(m, __shfl_xor(m, off));
  if ((tid & 63) == 0) red[tid >> 6] = m;
  __syncthreads();
  float mb = red[0];
  for (int w = 1; w < 8; ++w) mb = fmaxf(mb, red[w]);
  float s = 0.f;
#pragma unroll
  for (int i = 0; i < 4; ++i) {
    const float ex = expf(e4[i] - mb);
    att[i * 512 + tid] = ex;
    s += ex;
  }
  for (int off = 32; off; off >>= 1) s += __shfl_xor(s, off);
  if ((tid & 63) == 0) red[8 + (tid >> 6)] = s;
  __syncthreads();
  float inv = red[8];
  for (int w = 1; w < 8; ++w) inv += red[8 + w];
  inv = 1.0f / inv;
  const int v4 = tid & 15, tsub = tid >> 4;    // 16 v-quads x 32 t-lanes
  float4 acc = make_float4(0.f, 0.f, 0.f, 0.f);
  const float* vbase = values + (size_t)b * VDIM + vhalf * 64 + v4 * 4;
  for (int i = 0; i < 64; ++i) {
    const int t = i * 32 + tsub;
    const float a = att[t];
    const float4 val = *(const float4*)(vbase + (size_t)t * BATCH * VDIM);
    acc.x += a * val.x; acc.y += a * val.y; acc.z += a * val.z; acc.w += a * val.w;
  }
  *(float4*)(redv + (tsub * 17 + v4) * 4) = acc;
  __syncthreads();
  if (tid < 16) {
    float4 s4 = *(float4*)(redv + tid * 4);
    for (int p = 1; p < 32; ++p) {               // fixed order -> deterministic
      const float4 r = *(float4*)(redv + (p * 17 + tid) * 4);
      s4.x += r.x; s4.y += r.y; s4.z += r.z; s4.w += r.w;
    }
    s4.x *= inv; s4.y *= inv; s4.z *= inv; s4.w *= inv;
    *(float4*)(ctx + b * VDIM + vhalf * 64 + tid * 4) = s4;
  }
}

// gates GEMM: 240 active blocks = 8 bT(16 b) x 30 jT(40 j); x staged in LDS.
__device__ __forceinline__ void phase_gates(
    const float* __restrict__ emb, const int* __restrict__ chars_,
    const float* __restrict__ ctx, const float* __restrict__ h,
    const float* __restrict__ W_ih, const float* __restrict__ b_ih,
    const float* __restrict__ W_hh, const float* __restrict__ b_hh,
    float* __restrict__ gates, float* smem, int blk, int tid) {
  if (blk >= 240) return;
  const int bT  = (blk / 30) * 16;
  const int jTr = (blk % 30) * 40;
  float* Xs = smem;                       // 16 x 836 (stride%32==4: 2-way max, free)
  for (int bb = 0; bb < 16; ++bb) {
    const int bg = bT + bb;
    const int ch = chars_[bg];
    for (int k = tid; k < 832; k += NTHR) {
      float x;
      if (k < EDIM)             x = emb[ch * EDIM + k];
      else if (k < EDIM + VDIM) x = ctx[bg * VDIM + (k - EDIM)];
      else if (k < 828)         x = h[bg * HDIM + (k - 528)];
      else                      x = 0.f;
      Xs[bb * 836 + k] = x;
    }
  }
  __syncthreads();
  const int bLoc = tid & 15, jl = tid >> 4;   // 16 b x 32 j-lanes
  const int bg = bT + bLoc;
  const float4* xr = (const float4*)(Xs + bLoc * 836);
  const float4* xh = (const float4*)(Xs + bLoc * 836 + 528);
  for (int rr = 0; rr < 2; ++rr) {
    if (rr == 1 && jl >= 8) break;            // 40 rows: lanes 0..7 take 2nd row
    const int j = jTr + jl + rr * 32;
    float acc = 0.f;
    const float4* w0 = (const float4*)(W_ih + (size_t)j * 528);
    for (int k4 = 0; k4 < 132; ++k4) {        // identical order to R1 (passed)
      const float4 xv = xr[k4];
      const float4 wv = w0[k4];
      acc += xv.x * wv.x + xv.y * wv.y + xv.z * wv.z + xv.w * wv.w;
    }
    const float4* w1 = (const float4*)(W_hh + (size_t)j * 300);
    for (int k4 = 0; k4 < 75; ++k4) {
      const float4 xv = xh[k4];
      const float4 wv = w1[k4];
      acc += xv.x * wv.x + xv.y * wv.y + xv.z * wv.z + xv.w * wv.w;
    }
    gates[bg * GDIM + j] = acc + b_ih[j] + b_hh[j];
  }
}

// LSTM cell + logits + argmax + query: 128 active blocks (one per b).
__device__ __forceinline__ void phase_cell(
    const float* __restrict__ gates, const float* __restrict__ ctx,
    const float* __restrict__ W_proj, const float* __restrict__ b_proj,
    const float* __restrict__ b_phi, const float* __restrict__ wphiT,
    float* __restrict__ h, float* __restrict__ c,
    float* __restrict__ query, int* __restrict__ chars_,
    float* __restrict__ out, int step, float* smem, int blk, int tid) {
  if (blk >= BATCH) return;
  const int b = blk;
  float* cat_s   = smem;          // 428: [h_new(300) | ctx(128)]
  float* logit_s = smem + 432;    // 33
  if (tid < HDIM) {
    const float gi = gates[b * GDIM + tid];
    const float gf = gates[b * GDIM + HDIM + tid];
    const float gg = gates[b * GDIM + 2 * HDIM + tid];
    const float go = gates[b * GDIM + 3 * HDIM + tid];
    const float cc = c[b * HDIM + tid];
    const float si = 1.f / (1.f + expf(-gi));
    const float sf = 1.f / (1.f + expf(-gf));
    const float so = 1.f / (1.f + expf(-go));
    const float cn = sf * cc + si * tanhf(gg);
    const float hn = so * tanhf(cn);
    c[b * HDIM + tid] = cn;
    h[b * HDIM + tid] = hn;
    cat_s[tid] = hn;
  }
  if (tid < VDIM) cat_s[HDIM + tid] = ctx[b * VDIM + tid];
  __syncthreads();
  {
    const int w = tid >> 6, l = tid & 63;
    for (int j = w; j < NVOCAB; j += 8) {
      float p = 0.f;
      for (int e = l; e < HDIM + VDIM; e += 64) p += cat_s[e] * W_proj[j * 428 + e];
      p += __shfl_xor(p, 1); p += __shfl_xor(p, 2); p += __shfl_xor(p, 4);
      p += __shfl_xor(p, 8); p += __shfl_xor(p, 16); p += __shfl_xor(p, 32);
      if (l == 0) logit_s[j] = p + b_proj[j];
    }
  }
  __syncthreads();
  if (tid < NVOCAB) out[((size_t)step * BATCH + b) * NVOCAB + tid] = logit_s[tid];
  if (tid == 0) {
    float best = logit_s[0];
    int bi = 0;
    for (int j = 1; j < NVOCAB; ++j)
      if (logit_s[j] > best) { best = logit_s[j]; bi = j; }   // first-max, np semantics
    chars_[b] = bi;
    out[NLOGITS + (size_t)step * BATCH + b] = (float)bi;
  }
  if (tid < KDIM) {
    float q = b_phi[tid];
    for (int j = 0; j < HDIM; ++j) q += cat_s[j] * wphiT[j * KDIM + tid];
    query[b * KDIM + tid] = q;
  }
}

// ---------------------------------------------------------------------------
__global__ __launch_bounds__(NTHR, 4) void k_persist(
    const float* __restrict__ keys, const float* __restrict__ values,
    const float* __restrict__ emb, const float* __restrict__ W_phi,
    const float* __restrict__ b_phi, const float* __restrict__ W_ih,
    const float* __restrict__ b_ih, const float* __restrict__ W_hh,
    const float* __restrict__ b_hh, const float* __restrict__ W_proj,
    const float* __restrict__ b_proj, const float* __restrict__ h0,
    const float* __restrict__ c0,
    float* h, float* c, float* gates, float* query, float* energy, float* ctx,
    float* wphiT, int* chars_, unsigned* bar, float* out) {
  __shared__ __align__(16) float smem[16 * 836];   // 53.5 KB (union of all phases)
  const int blk = blockIdx.x;
  const int tid = threadIdx.x;
  unsigned tgt = 0;

  // phase -1: transpose W_phi, init h/c/chars (single grid-stride pass)
  {
    const int i = blk * NTHR + tid;                 // covers 0..131071
    if (i < HDIM * KDIM) { const int j = i >> 7, kq = i & 127; wphiT[i] = W_phi[kq * HDIM + j]; }
    if (i < BATCH * HDIM) { const int j = i % HDIM; h[i] = h0[j]; c[i] = c0[j]; }
    if (i < BATCH) chars_[i] = SOS_TOK;
  }
  tgt += NBLK; gbar(bar, tgt);
  // initial query = b_phi + h0 @ W_phi.T
  if (blk < BATCH && tid < KDIM) {
    float q = b_phi[tid];
    for (int j = 0; j < HDIM; ++j) q += h0[j] * wphiT[j * KDIM + tid];
    query[blk * KDIM + tid] = q;
  }
  tgt += NBLK; gbar(bar, tgt);
  phase_energy(keys, query, energy, blk, tid);
  tgt += NBLK; gbar(bar, tgt);
  phase_context(values, energy, ctx, smem, blk, tid);
  tgt += NBLK; gbar(bar, tgt);

#pragma unroll 1
  for (int step = 0; step < MAXLEN; ++step) {
    phase_gates(emb, chars_, ctx, h, W_ih, b_ih, W_hh, b_hh, gates, smem, blk, tid);
    tgt += NBLK; gbar(bar, tgt);
    phase_cell(gates, ctx, W_proj, b_proj, b_phi, wphiT, h, c, query, chars_, out,
               step, smem, blk, tid);
    tgt += NBLK; gbar(bar, tgt);
    phase_energy(keys, query, energy, blk, tid);
    tgt += NBLK; gbar(bar, tgt);
    phase_context(values, energy, ctx, smem, blk, tid);
    tgt += NBLK; gbar(bar, tgt);
  }
}

// ---------------------------------------------------------------------------
extern "C" void kernel_launch(void* const* d_in, const int* in_sizes, int n_in,
                              void* d_out, int out_size, void* d_ws, size_t ws_size,
                              hipStream_t stream) {
  (void)in_sizes; (void)n_in; (void)out_size; (void)ws_size;
  const float* keys   = (const float*)d_in[0];
  const float* values = (const float*)d_in[1];
  const float* emb    = (const float*)d_in[2];
  const float* W_phi  = (const float*)d_in[3];
  const float* b_phi  = (const float*)d_in[4];
  const float* W_ih   = (const float*)d_in[5];
  const float* b_ih   = (const float*)d_in[6];
  const float* W_hh   = (const float*)d_in[7];
  const float* b_hh   = (const float*)d_in[8];
  const float* W_proj = (const float*)d_in[9];
  const float* b_proj = (const float*)d_in[10];
  const float* h0     = (const float*)d_in[11];
  const float* c0     = (const float*)d_in[12];
  float* out = (float*)d_out;

  float* F = (float*)d_ws;
  float* f_h      = F + OFF_H;
  float* f_c      = F + OFF_C;
  float* f_gates  = F + OFF_GATES;
  float* f_query  = F + OFF_QUERY;
  float* f_energy = F + OFF_ENERGY;
  float* f_ctx    = F + OFF_CTX;
  float* f_wphiT  = F + OFF_WPHIT;
  int*   i_chars  = (int*)(F + OFF_CHARS);
  unsigned* bar   = (unsigned*)(F + OFF_BAR);

  // barrier counter must start at 0 (ws is poisoned 0xAA before every launch)
  hipMemsetAsync(bar, 0, sizeof(unsigned), stream);

  k_persist<<<NBLK, NTHR, 0, stream>>>(
      keys, values, emb, W_phi, b_phi, W_ih, b_ih, W_hh, b_hh, W_proj, b_proj,
      h0, c0, f_h, f_c, f_gates, f_query, f_energy, f_ctx, f_wphiT, i_chars,
      bar, out);
}

// Round 4
// 53408.722 us; speedup vs baseline: 7.0392x; 7.0392x over previous
//
#include <hip/hip_runtime.h>
#include <math.h>

// ---- problem constants ----
constexpr int SEQ_T  = 2048;
constexpr int BATCH  = 128;
constexpr int KDIM   = 128;
constexpr int VDIM   = 128;
constexpr int EDIM   = 400;
constexpr int HDIM   = 300;
constexpr int GDIM   = 1200;    // 4*H
constexpr int NVOCAB = 33;
constexpr int MAXLEN = 500;
constexpr int SOS_TOK = 5;
constexpr int NCHUNK = 16;      // t-chunks per b
constexpr int CHT    = 128;     // t per chunk
constexpr int PROW   = 136;     // floats per partial row: accV[128], M, S, pad
constexpr long long NLOGITS = (long long)MAXLEN * BATCH * NVOCAB; // 2,112,000

// ---- ws float-element offsets ----
constexpr size_t OFF_H     = 0;        // 128*300
constexpr size_t OFF_C0    = 38400;    // 128*300 (ping)
constexpr size_t OFF_C1    = 76800;    // 128*300 (pong)
constexpr size_t OFF_GATES = 115200;   // 128*1200
constexpr size_t OFF_QUERY = 268800;   // 128*128 (used only for step -1)
constexpr size_t OFF_CTX   = 285184;   // 128*128
constexpr size_t OFF_WPHIT = 301568;   // 300*128
constexpr size_t OFF_PART  = 339968;   // 2048*136
constexpr size_t OFF_CHARS = 618496;   // 128 int

// ---------------------------------------------------------------------------
// one-time: W_phi [128][300] -> W_phiT [300][128] (proven R1)
__global__ __launch_bounds__(256) void k_transpose(
    const float* __restrict__ W_phi, float* __restrict__ wphiT) {
  int i = blockIdx.x * 256 + threadIdx.x;
  if (i < HDIM * KDIM) {
    int j = i >> 7, kq = i & 127;
    wphiT[i] = W_phi[kq * HDIM + j];
  }
}

// one-time: h,c,chars init + initial query (proven R1)
__global__ __launch_bounds__(128) void k_init(
    const float* __restrict__ h0, const float* __restrict__ c0,
    const float* __restrict__ b_phi, const float* __restrict__ wphiT,
    float* __restrict__ h, float* __restrict__ c,
    float* __restrict__ query, int* __restrict__ chars_) {
  const int b = blockIdx.x;
  const int tid = threadIdx.x;
  for (int j = tid; j < HDIM; j += 128) {
    h[b * HDIM + j] = h0[j];
    c[b * HDIM + j] = c0[j];
  }
  {
    float q = b_phi[tid];
    for (int j = 0; j < HDIM; ++j) q += h0[j] * wphiT[j * KDIM + tid];
    query[b * KDIM + tid] = q;
  }
  if (tid == 0) chars_[b] = SOS_TOK;
}

// ---------------------------------------------------------------------------
// k_att: fused [cell -> logits/argmax (chunk0) -> query -> chunked attention].
// grid (128 b, 16 chunk), 256 threads. Streams keys+values slices (BW-bound).
// step == -1: initial attend(h0) -- skip cell/logits, read query from global.
__global__ __launch_bounds__(256) void k_att(
    const float* __restrict__ keys, const float* __restrict__ values,
    const float* __restrict__ gates, const float* __restrict__ ctx_g,
    const float* __restrict__ W_proj, const float* __restrict__ b_proj,
    const float* __restrict__ b_phi, const float* __restrict__ wphiT,
    const float* __restrict__ c_in, float* __restrict__ c_out,
    float* __restrict__ h, const float* __restrict__ query_g,
    int* __restrict__ chars_, float* __restrict__ partials,
    float* __restrict__ out, int step) {
  const int b = blockIdx.x, chunk = blockIdx.y, tid = threadIdx.x;
  __shared__ float hs_cat[HDIM + VDIM];   // [h_new 300 | ctx 128(chunk0 only)]
  __shared__ float logit_s[NVOCAB];
  __shared__ float qs[KDIM];
  __shared__ float e_s[CHT];
  __shared__ float att[CHT];
  __shared__ float red[8];
  __shared__ __align__(16) float redv[8 * 33 * 4];

  if (step >= 0) {
    // ---- LSTM cell (redundant per chunk; identical fp ops -> identical h) ----
    for (int j = tid; j < HDIM; j += 256) {
      const float gi = gates[b * GDIM + j];
      const float gf = gates[b * GDIM + HDIM + j];
      const float gg = gates[b * GDIM + 2 * HDIM + j];
      const float go = gates[b * GDIM + 3 * HDIM + j];
      const float cc = c_in[b * HDIM + j];
      const float si = 1.f / (1.f + expf(-gi));
      const float sf = 1.f / (1.f + expf(-gf));
      const float so = 1.f / (1.f + expf(-go));
      const float cn = sf * cc + si * tanhf(gg);
      const float hn = so * tanhf(cn);
      hs_cat[j] = hn;
      if (chunk == 0) { c_out[b * HDIM + j] = cn; h[b * HDIM + j] = hn; }
    }
    if (chunk == 0 && tid < VDIM) hs_cat[HDIM + tid] = ctx_g[b * VDIM + tid];
    __syncthreads();
    if (chunk == 0) {
      // ---- logits + argmax + emit (single writer: chunk0) ----
      const int w = tid >> 6, l = tid & 63;
      for (int j = w; j < NVOCAB; j += 4) {
        float p = 0.f;
        for (int e = l; e < HDIM + VDIM; e += 64) p += hs_cat[e] * W_proj[j * 428 + e];
        p += __shfl_xor(p, 1); p += __shfl_xor(p, 2); p += __shfl_xor(p, 4);
        p += __shfl_xor(p, 8); p += __shfl_xor(p, 16); p += __shfl_xor(p, 32);
        if (l == 0) logit_s[j] = p + b_proj[j];
      }
      __syncthreads();
      if (tid < NVOCAB) out[((size_t)step * BATCH + b) * NVOCAB + tid] = logit_s[tid];
      if (tid == 0) {
        float best = logit_s[0];
        int bi = 0;
        for (int j = 1; j < NVOCAB; ++j)
          if (logit_s[j] > best) { best = logit_s[j]; bi = j; }  // np first-max
        chars_[b] = bi;
        out[NLOGITS + (size_t)step * BATCH + b] = (float)bi;
      }
    }
    // ---- query from h_new (identical to R1 k_fused2 stage 4) ----
    if (tid < KDIM) {
      float q = b_phi[tid];
      for (int j = 0; j < HDIM; ++j) q += hs_cat[j] * wphiT[j * KDIM + tid];
      qs[tid] = q;
    }
  } else {
    if (tid < KDIM) qs[tid] = query_g[b * KDIM + tid];
  }
  __syncthreads();

  // ---- energy over this chunk's 128 t (inner dot identical to R1) ----
  const int wave = tid >> 6, lane = tid & 63;
  const int half = lane >> 5, l32 = lane & 31;
  {
    const float4 q4 = *(const float4*)(qs + l32 * 4);
    const int tl0 = wave * 32;
    for (int i = 0; i < 16; ++i) {
      const int tl = tl0 + 2 * i + half;
      const int t = chunk * CHT + tl;
      const float4 kv = *(const float4*)(keys + ((size_t)t * BATCH + b) * KDIM + l32 * 4);
      float p = q4.x * kv.x + q4.y * kv.y + q4.z * kv.z + q4.w * kv.w;
      p += __shfl_xor(p, 1); p += __shfl_xor(p, 2); p += __shfl_xor(p, 4);
      p += __shfl_xor(p, 8); p += __shfl_xor(p, 16);
      if (l32 == 0) e_s[tl] = p;
    }
  }
  __syncthreads();

  // ---- chunk-local softmax stats (M_c, S_c) ----
  float m = (tid < CHT) ? e_s[tid] : -INFINITY;
  for (int off = 32; off; off >>= 1) m = fmaxf(m, __shfl_xor(m, off));
  if ((tid & 63) == 0) red[tid >> 6] = m;
  __syncthreads();
  const float M = fmaxf(fmaxf(red[0], red[1]), fmaxf(red[2], red[3]));
  float ex = 0.f;
  if (tid < CHT) { ex = expf(e_s[tid] - M); att[tid] = ex; }
  for (int off = 32; off; off >>= 1) ex += __shfl_xor(ex, off);
  if ((tid & 63) == 0) red[4 + (tid >> 6)] = ex;
  __syncthreads();
  const float S = red[4] + red[5] + red[6] + red[7];

  // ---- unnormalized weighted V accumulation over chunk ----
  const int v4 = tid & 31, tsub = tid >> 5;     // 32 quads x 8 t-lanes
  float4 acc = make_float4(0.f, 0.f, 0.f, 0.f);
  const float* vb = values + (size_t)b * VDIM + v4 * 4;
  for (int i = 0; i < 16; ++i) {
    const int tl = i * 8 + tsub;
    const float a = att[tl];
    const float4 val = *(const float4*)(vb + (size_t)(chunk * CHT + tl) * BATCH * VDIM);
    acc.x += a * val.x; acc.y += a * val.y; acc.z += a * val.z; acc.w += a * val.w;
  }
  *(float4*)(redv + (tsub * 33 + v4) * 4) = acc;
  __syncthreads();
  const size_t r = (size_t)b * NCHUNK + chunk;
  if (tid < 32) {
    float4 s4 = *(const float4*)(redv + tid * 4);
    for (int p = 1; p < 8; ++p) {               // fixed order -> deterministic
      const float4 rr = *(const float4*)(redv + (p * 33 + tid) * 4);
      s4.x += rr.x; s4.y += rr.y; s4.z += rr.z; s4.w += rr.w;
    }
    *(float4*)(partials + r * PROW + tid * 4) = s4;
  }
  if (tid == 0) {
    partials[r * PROW + 128] = M;
    partials[r * PROW + 129] = S;
  }
}

// ---------------------------------------------------------------------------
// k_gates: [combine partials -> ctx] + gates GEMM (R1 proven geometry).
// grid (8 bT, 38 jT), 256 threads. blockIdx.y==0 column also publishes ctx.
__global__ __launch_bounds__(256) void k_gates(
    const float* __restrict__ emb, const int* __restrict__ chars_,
    const float* __restrict__ partials, const float* __restrict__ h,
    const float* __restrict__ W_ih, const float* __restrict__ b_ih,
    const float* __restrict__ W_hh, const float* __restrict__ b_hh,
    float* __restrict__ gates, float* __restrict__ ctx_g) {
  const int bT = blockIdx.x * 16;
  const int jT = blockIdx.y * 32;
  const int tid = threadIdx.x;
  __shared__ float Xs[16 * 836];
  __shared__ float ctxs[16 * 128];
  // ---- combine: ctx[b] from 16 chunk partials (deterministic fixed order) ----
  {
    const int bl = tid >> 4, l16 = tid & 15;    // 16 b x 16 lanes(8 dims each)
    const int bg = bT + bl;
    const float* pb = partials + (size_t)bg * NCHUNK * PROW;
    float M = -INFINITY;
    for (int ci = 0; ci < NCHUNK; ++ci) M = fmaxf(M, pb[ci * PROW + 128]);
    float den = 0.f;
    float4 n0 = make_float4(0.f, 0.f, 0.f, 0.f);
    float4 n1 = make_float4(0.f, 0.f, 0.f, 0.f);
    for (int ci = 0; ci < NCHUNK; ++ci) {
      const float w = expf(pb[ci * PROW + 128] - M);
      den += w * pb[ci * PROW + 129];
      const float4 a0 = *(const float4*)(pb + ci * PROW + l16 * 8);
      const float4 a1 = *(const float4*)(pb + ci * PROW + l16 * 8 + 4);
      n0.x += w * a0.x; n0.y += w * a0.y; n0.z += w * a0.z; n0.w += w * a0.w;
      n1.x += w * a1.x; n1.y += w * a1.y; n1.z += w * a1.z; n1.w += w * a1.w;
    }
    const float inv = 1.f / den;
    n0.x *= inv; n0.y *= inv; n0.z *= inv; n0.w *= inv;
    n1.x *= inv; n1.y *= inv; n1.z *= inv; n1.w *= inv;
    *(float4*)(ctxs + bl * 128 + l16 * 8)     = n0;
    *(float4*)(ctxs + bl * 128 + l16 * 8 + 4) = n1;
    if (blockIdx.y == 0) {
      *(float4*)(ctx_g + bg * 128 + l16 * 8)     = n0;
      *(float4*)(ctx_g + bg * 128 + l16 * 8 + 4) = n1;
    }
  }
  __syncthreads();
  // ---- stage x = [emb | ctx | h] (ctx from LDS combine result) ----
  for (int bb = 0; bb < 16; ++bb) {
    const int bg = bT + bb;
    const int ch = chars_[bg];
    for (int k = tid; k < 832; k += 256) {
      float x;
      if (k < EDIM)      x = emb[ch * EDIM + k];
      else if (k < 528)  x = ctxs[bb * 128 + (k - EDIM)];
      else if (k < 828)  x = h[bg * HDIM + (k - 528)];
      else               x = 0.f;
      Xs[bb * 836 + k] = x;
    }
  }
  __syncthreads();
  // ---- gates GEMM (verbatim R1, proven) ----
  const int bLoc = tid & 15;
  const int jLoc = tid >> 4;
  const int j0 = jT + jLoc * 2;
  if (j0 >= GDIM) return;
  const int j1 = j0 + 1;
  const int bg = bT + bLoc;
  float acc0 = 0.f, acc1 = 0.f;
  const float4* xr = (const float4*)(Xs + bLoc * 836);
  {
    const float4* w0 = (const float4*)(W_ih + (size_t)j0 * 528);
    const float4* w1 = (const float4*)(W_ih + (size_t)j1 * 528);
    for (int k4 = 0; k4 < 132; ++k4) {
      const float4 xv = xr[k4];
      const float4 a = w0[k4];
      const float4 bv = w1[k4];
      acc0 += xv.x * a.x + xv.y * a.y + xv.z * a.z + xv.w * a.w;
      acc1 += xv.x * bv.x + xv.y * bv.y + xv.z * bv.z + xv.w * bv.w;
    }
  }
  {
    const float4* xh = (const float4*)(Xs + bLoc * 836 + 528);
    const float4* g0 = (const float4*)(W_hh + (size_t)j0 * HDIM);
    const float4* g1 = (const float4*)(W_hh + (size_t)j1 * HDIM);
    for (int k4 = 0; k4 < 75; ++k4) {
      const float4 xv = xh[k4];
      const float4 a = g0[k4];
      const float4 bv = g1[k4];
      acc0 += xv.x * a.x + xv.y * a.y + xv.z * a.z + xv.w * a.w;
      acc1 += xv.x * bv.x + xv.y * bv.y + xv.z * bv.z + xv.w * bv.w;
    }
  }
  gates[bg * GDIM + j0] = acc0 + b_ih[j0] + b_hh[j0];
  gates[bg * GDIM + j1] = acc1 + b_ih[j1] + b_hh[j1];
}

// ---------------------------------------------------------------------------
extern "C" void kernel_launch(void* const* d_in, const int* in_sizes, int n_in,
                              void* d_out, int out_size, void* d_ws, size_t ws_size,
                              hipStream_t stream) {
  (void)in_sizes; (void)n_in; (void)out_size; (void)ws_size;
  const float* keys   = (const float*)d_in[0];
  const float* values = (const float*)d_in[1];
  const float* emb    = (const float*)d_in[2];
  const float* W_phi  = (const float*)d_in[3];
  const float* b_phi  = (const float*)d_in[4];
  const float* W_ih   = (const float*)d_in[5];
  const float* b_ih   = (const float*)d_in[6];
  const float* W_hh   = (const float*)d_in[7];
  const float* b_hh   = (const float*)d_in[8];
  const float* W_proj = (const float*)d_in[9];
  const float* b_proj = (const float*)d_in[10];
  const float* h0     = (const float*)d_in[11];
  const float* c0     = (const float*)d_in[12];
  float* out = (float*)d_out;

  float* F = (float*)d_ws;
  float* f_h     = F + OFF_H;
  float* f_c[2]  = {F + OFF_C0, F + OFF_C1};
  float* f_gates = F + OFF_GATES;
  float* f_query = F + OFF_QUERY;
  float* f_ctx   = F + OFF_CTX;
  float* f_wphiT = F + OFF_WPHIT;
  float* f_part  = F + OFF_PART;
  int*   i_chars = (int*)(F + OFF_CHARS);

  k_transpose<<<150, 256, 0, stream>>>(W_phi, f_wphiT);
  k_init<<<BATCH, 128, 0, stream>>>(h0, c0, b_phi, f_wphiT, f_h, f_c[0],
                                    f_query, i_chars);
  // initial attend(h0): query from global, no cell/logits
  k_att<<<dim3(BATCH, NCHUNK), 256, 0, stream>>>(
      keys, values, f_gates, f_ctx, W_proj, b_proj, b_phi, f_wphiT,
      f_c[0], f_c[1], f_h, f_query, i_chars, f_part, out, -1);

  for (int s = 0; s < MAXLEN; ++s) {
    k_gates<<<dim3(8, 38), 256, 0, stream>>>(
        emb, i_chars, f_part, f_h, W_ih, b_ih, W_hh, b_hh, f_gates, f_ctx);
    k_att<<<dim3(BATCH, NCHUNK), 256, 0, stream>>>(
        keys, values, f_gates, f_ctx, W_proj, b_proj, b_phi, f_wphiT,
        f_c[s & 1], f_c[(s + 1) & 1], f_h, f_query, i_chars, f_part, out, s);
  }
}